// Round 4
// baseline (235.256 us; speedup 1.0000x reference)
//
#include <hip/hip_runtime.h>

// LIF activation: x [B=64, T=500, C=1024] fp32, scalars w_input, w_leak.
// Per (b,c): forget=(Vm<1); Vm=relu(wi*x_t + kl*Vm*forget); spike=(Vm>1).
// 65536 serial sequences -> 1024 compute waves (fixed by shape).
//
// History:
//  R2 (reg), R4 (LDS+drain), R6 (barrier-free counted vmcnt), R7
//  (producer/consumer 8 waves + 4x-wide stores): ALL ~82 us, 2.4 TB/s.
//  Store width, sync discipline, wave count: all ruled out. The invariant
//  left: per-CU in-flight load bytes ~40-60 KB and per-CU BW stuck at
//  ~12 GB/s logical, while fill/copy kernels sustain ~25 GB/s/CU on the
//  same chip. Theory: throughput = inflight/latency with heavily-queued
//  (us-scale) loaded latency; every variant so far kept the same window.
//  R8 (this): 2-3x deeper window. R6 single-role wave-private structure
//  + R7's wide-store path (5 stores/chunk via LDS restage, frees the
//  in-order vmcnt ledger) -> 6-chunk-deep prefetch, 7 LDS buffers:
//  30 loads (30 KB) in flight per wave, 120 KB per CU. Peak vmcnt 40<63.
//  LDS 7*20KB + 1KB = 145 KB <= 160. If dur is unchanged, depth is NOT
//  the limiter and the ceiling is the access pattern itself -> next:
//  per-CU contiguous streams / speculative time segmentation.
//
// Per-wave vmcnt ledger (5 loads L + 5 stores S per chunk; prologue
// stages chunks 0..5 = 30 loads; stage(k+6) at iter k):
//   k=0    : newer than L0 = L1..L5 (25)            -> VMWAIT(25)
//   k=1..19: newer than Lk = S{k-1}(5)+L{k+1..k+5}  -> VMWAIT(30)
//   k=20..24: 25,20,15,10,5 (no more staging)
// Buffer reuse: stage at iter k overwrites buf (k+6)%7 == (k-1)%7, whose
// chunk this wave consumed at iter k-1 (data deps resolved its ds_reads
// before the dependent stores issued). Wave-private slices: no cross-wave
// hazard, no barriers anywhere.
//
// __fmul_rn/__fadd_rn: spikes are exact step functions vs threshold 1.0;
// must match numpy's unfused fp32 op-by-op arithmetic (absmax=0 so far).

#define LIF_B 64
#define LIF_T 500
#define LIF_C 1024
#define LIF_TC 20                  // timesteps per chunk
#define LIF_NCH 25                 // 500 / 20
#define LIF_NBUF 7                 // 7 x 20 KB x-buffers (deep prefetch)

typedef float vfloat4 __attribute__((ext_vector_type(4)));

// global_load_lds: per-lane global src, wave-uniform LDS base; HW writes
// LDS at base + lane*16. Launder generic->AS pointers via uintptr_t.
#define GLOBAL_AS(p) ((__attribute__((address_space(1))) const void*)(uintptr_t)(p))
#define LDS_AS(p)    ((__attribute__((address_space(3))) void*)(uintptr_t)(p))

// Counted wait. "memory" clobber pins all memory ops (LDS reads/writes,
// stores, load_lds issues) on their side of the wait.
#define VMWAIT(n) asm volatile("s_waitcnt vmcnt(" #n ")" ::: "memory")

__global__ __launch_bounds__(256) void lif_kernel(
    const float* __restrict__ x,
    const float* __restrict__ w_input_p,
    const float* __restrict__ w_leak_p,
    float* __restrict__ out) {

  // x chunks: [buf][wave-slice][row*64+chan]. 7 x 4 x 5 KB = 140 KB.
  __shared__ __align__(16) float lds_x[LIF_NBUF][4][LIF_TC * 64];
  // spike staging: [wave-slice][4 rows * 64 chans]. 4 KB.
  __shared__ __align__(16) float sp[4][4 * 64];

  const int b     = blockIdx.x >> 2;          // 64 b-rows
  const int cbase = (blockIdx.x & 3) << 8;    // 4 channel groups of 256
  const int tidx  = threadIdx.x;              // 0..255
  const int w     = tidx >> 6;                // wave 0..3
  const int lane  = tidx & 63;

  const float wi = w_input_p[0];
  const float kl = __fsub_rn(1.0f, w_leak_p[0]);  // 1 - w_leak
  // Drain arg loads so the vmcnt ledger starts from a clean zero.
  asm volatile("s_waitcnt vmcnt(0) lgkmcnt(0)" ::: "memory");

  const float* xblk = x   + (size_t)b * LIF_T * LIF_C + cbase;
  float*       oblk = out + (size_t)b * LIF_T * LIF_C + cbase;

  // Wave w stages chunk k's channels [64w,64w+64) into its slice of
  // lds_x[p]: 5 load_lds, each 4 rows x 16 chans-of-16B. Lane l: global
  // row r0+(l>>4), chan 64w+(l&15)*4; LDS lands at slice + l*16 B, i.e.
  // row-major [20][64]. Verified absmax=0 in R6/R7.
  auto stage = [&](int k, int p) {
    const float* src0 = xblk + (size_t)k * LIF_TC * LIF_C
                      + (w << 6) + ((lane & 15) << 2);
#pragma unroll
    for (int r0 = 0; r0 < LIF_TC; r0 += 4) {
      const float* g = src0 + (size_t)(r0 + (lane >> 4)) * LIF_C;
      float* l = &lds_x[p][w][r0 * 64];                // wave-uniform base
      __builtin_amdgcn_global_load_lds(GLOBAL_AS(g), LDS_AS(l), 16, 0, 0);
    }
    __builtin_amdgcn_sched_barrier(0);   // keep the 5 issues as one cluster
  };

  float Vm = 0.0f;

  auto compute = [&](int k, int p) {
    float* obase = oblk + (size_t)k * LIF_TC * LIF_C + (w << 6);
#pragma unroll
    for (int r0 = 0; r0 < LIF_TC; r0 += 4) {
#pragma unroll
      for (int dr = 0; dr < 4; ++dr) {
        const float xt  = lds_x[p][w][(r0 + dr) * 64 + lane];
        const float acc = (Vm < 1.0f) ? __fmul_rn(kl, Vm) : 0.0f;
        const float v   = __fadd_rn(__fmul_rn(wi, xt), acc);
        Vm = fmaxf(v, 0.0f);
        sp[w][dr * 64 + lane] = (Vm > 1.0f) ? 1.0f : 0.0f;
      }
      // Flush 4 rows x 64 chans as one dwordx4 per lane: lane l covers
      // row r0+(l>>4), chans (l&15)*4..+4 of this wave's 64-chan slice.
      const vfloat4 v4 =
          *reinterpret_cast<const vfloat4*>(&sp[w][lane << 2]);
      float* gdst = obase + (size_t)(r0 + (lane >> 4)) * LIF_C
                  + ((lane & 15) << 2);
      __builtin_nontemporal_store(v4, reinterpret_cast<vfloat4*>(gdst));
    }
    __builtin_amdgcn_sched_barrier(0);   // stores stay inside this region
  };

  // Prologue: 6 chunks in flight (30 loads).
  stage(0, 0); stage(1, 1); stage(2, 2);
  stage(3, 3); stage(4, 4); stage(5, 5);

  // k = 0
  VMWAIT(25);
  stage(6, 6);
  compute(0, 0);

  // k = 1 .. 18 (steady state; chunk j lives in buffer j % 7)
  {
    int ps = 6, pc = 0;  // last staged buf, last computed buf
    for (int k = 1; k <= 18; ++k) {
      VMWAIT(30);
      if (++ps == LIF_NBUF) ps = 0;    // (k+6) % 7
      stage(k + 6, ps);
      if (++pc == LIF_NBUF) pc = 0;    // k % 7
      compute(k, pc);
    }
  }

  // k = 19 .. 24: drain tail (no more staging). Buffers: k % 7.
  VMWAIT(30); compute(19, 5);
  VMWAIT(25); compute(20, 6);
  VMWAIT(20); compute(21, 0);
  VMWAIT(15); compute(22, 1);
  VMWAIT(10); compute(23, 2);
  VMWAIT(5);  compute(24, 3);
}

extern "C" void kernel_launch(void* const* d_in, const int* in_sizes, int n_in,
                              void* d_out, int out_size, void* d_ws, size_t ws_size,
                              hipStream_t stream) {
  const float* x  = (const float*)d_in[0];
  const float* wi = (const float*)d_in[1];
  const float* wl = (const float*)d_in[2];
  float* out = (float*)d_out;

  const int grid = LIF_B * (LIF_C / 256);  // 64 * 4 = 256 blocks, 1/CU
  lif_kernel<<<grid, 256, 0, stream>>>(x, wi, wl, out);
}